// Round 7
// baseline (116.483 us; speedup 1.0000x reference)
//
#include <hip/hip_runtime.h>

constexpr int B = 32;
constexpr int T = 128;
constexpr int N = 4096;
constexpr int UNR = 8;           // time-steps per pipeline group
constexpr int NG  = T / UNR;     // 16 groups

typedef float f32x4 __attribute__((ext_vector_type(4)));

__global__ __launch_bounds__(128) void lif_scan_kernel(
    const float* __restrict__ x,
    const float* __restrict__ tau_mem,
    const float* __restrict__ v_th,
    float* __restrict__ out)
{
    const int tid = blockIdx.x * blockDim.x + threadIdx.x;   // 0 .. B*N/4-1
    const int b   = tid >> 10;               // / (N/4)
    const int n4  = (tid & 1023) * 4;        // neuron quad index

    // per-neuron params: clip in fp32 exactly like the reference, then promote
    const f32x4 tm = *reinterpret_cast<const f32x4*>(tau_mem + n4);
    const f32x4 tv = *reinterpret_cast<const f32x4*>(v_th + n4);

    double t[4], c[4], h[4], is[4], v[4];
#pragma unroll
    for (int k = 0; k < 4; ++k) {
        t[k] = (double)fminf(fmaxf(tm[k], 0.8f), 0.98f);
        c[k] = 1.0 - t[k];
        h[k] = (double)fminf(fmaxf(tv[k], 0.05f), 0.5f);
        is[k] = 0.0;
        v[k]  = 0.0;
    }

    const size_t base = (size_t)b * T * N + (size_t)n4;
    const float* xp = x + base;
    float*       op = out + base;

    f32x4 buf[UNR];
#pragma unroll
    for (int u = 0; u < UNR; ++u)
        buf[u] = *reinterpret_cast<const f32x4*>(xp + (size_t)u * N);

    for (int g = 0; g < NG; ++g) {
        f32x4 nbuf[UNR];
        if (g + 1 < NG) {
            const float* xg = xp + (size_t)(g + 1) * UNR * N;
#pragma unroll
            for (int u = 0; u < UNR; ++u)
                nbuf[u] = *reinterpret_cast<const f32x4*>(xg + (size_t)u * N);
        }

        float* og = op + (size_t)g * UNR * N;
#pragma unroll
        for (int u = 0; u < UNR; ++u) {
            f32x4 s;
#pragma unroll
            for (int k = 0; k < 4; ++k) {
                // i_syn[t] = 0.5 * i_syn[t-1] + x[t]
                is[k] = fma(0.5, is[k], (double)buf[u][k]);
                // v[t] = tau * v[t-1] + (1 - tau) * i_syn[t]
                v[k] = fma(t[k], v[k], c[k] * is[k]);
                s[k] = (v[k] >= h[k]) ? 1.0f : 0.0f;
            }
            __builtin_nontemporal_store(s, reinterpret_cast<f32x4*>(og + (size_t)u * N));
        }

#pragma unroll
        for (int u = 0; u < UNR; ++u) buf[u] = nbuf[u];
    }
}

extern "C" void kernel_launch(void* const* d_in, const int* in_sizes, int n_in,
                              void* d_out, int out_size, void* d_ws, size_t ws_size,
                              hipStream_t stream) {
    const float* x       = (const float*)d_in[0];
    const float* tau_mem = (const float*)d_in[1];
    const float* v_th    = (const float*)d_in[2];
    float* out           = (float*)d_out;

    const int threads = B * (N / 4);          // 32768
    dim3 block(128);
    dim3 grid(threads / 128);                 // 256 blocks -> 1 block/CU, 2 waves/CU
    lif_scan_kernel<<<grid, block, 0, stream>>>(x, tau_mem, v_th, out);
}

// Round 9
// 110.095 us; speedup vs baseline: 1.0580x; 1.0580x over previous
//
#include <hip/hip_runtime.h>

constexpr int B = 32;
constexpr int T = 128;
constexpr int N = 4096;
constexpr int UNR = 32;          // time-steps per pipeline group (deep burst)
constexpr int NG  = T / UNR;     // 4 groups

typedef float f32x2 __attribute__((ext_vector_type(2)));

__global__ __launch_bounds__(256) void lif_scan_kernel(
    const float* __restrict__ x,
    const float* __restrict__ tau_mem,
    const float* __restrict__ v_th,
    float* __restrict__ out)
{
    const int tid = blockIdx.x * blockDim.x + threadIdx.x;   // 0 .. B*N/2-1
    const int b   = tid >> 11;               // / (N/2)
    const int n2  = (tid & 2047) * 2;        // neuron pair index

    // per-neuron params: clip in fp32 exactly like the reference, then promote
    const f32x2 tm = *reinterpret_cast<const f32x2*>(tau_mem + n2);
    const f32x2 tv = *reinterpret_cast<const f32x2*>(v_th + n2);

    const double t0 = (double)fminf(fmaxf(tm.x, 0.8f), 0.98f);
    const double t1 = (double)fminf(fmaxf(tm.y, 0.8f), 0.98f);
    const double c0 = 1.0 - t0, c1 = 1.0 - t1;
    const double h0 = (double)fminf(fmaxf(tv.x, 0.05f), 0.5f);
    const double h1 = (double)fminf(fmaxf(tv.y, 0.05f), 0.5f);

    const size_t base = (size_t)b * T * N + (size_t)n2;
    const float* xp = x + base;
    float*       op = out + base;

    double is0 = 0.0, is1 = 0.0, v0 = 0.0, v1 = 0.0;

    f32x2 buf[UNR];
#pragma unroll
    for (int u = 0; u < UNR; ++u)
        buf[u] = *reinterpret_cast<const f32x2*>(xp + (size_t)u * N);

#pragma unroll
    for (int g = 0; g < NG; ++g) {
        f32x2 nbuf[UNR];
        if (g + 1 < NG) {
            const float* xg = xp + (size_t)(g + 1) * UNR * N;
#pragma unroll
            for (int u = 0; u < UNR; ++u)
                nbuf[u] = *reinterpret_cast<const f32x2*>(xg + (size_t)u * N);
        }

        float* og = op + (size_t)g * UNR * N;
#pragma unroll
        for (int u = 0; u < UNR; ++u) {
            // i_syn[t] = 0.5 * i_syn[t-1] + x[t]
            is0 = fma(0.5, is0, (double)buf[u].x);
            is1 = fma(0.5, is1, (double)buf[u].y);
            // v[t] = tau * v[t-1] + (1 - tau) * i_syn[t]
            v0 = fma(t0, v0, c0 * is0);
            v1 = fma(t1, v1, c1 * is1);
            f32x2 s;
            s.x = (v0 >= h0) ? 1.0f : 0.0f;
            s.y = (v1 >= h1) ? 1.0f : 0.0f;
            __builtin_nontemporal_store(s, reinterpret_cast<f32x2*>(og + (size_t)u * N));
        }

        // fully-unrolled outer loop: compiler ping-pongs buffers, no v_mov copies
#pragma unroll
        for (int u = 0; u < UNR; ++u) buf[u] = nbuf[u];
    }
}

extern "C" void kernel_launch(void* const* d_in, const int* in_sizes, int n_in,
                              void* d_out, int out_size, void* d_ws, size_t ws_size,
                              hipStream_t stream) {
    const float* x       = (const float*)d_in[0];
    const float* tau_mem = (const float*)d_in[1];
    const float* v_th    = (const float*)d_in[2];
    float* out           = (float*)d_out;

    const int threads = B * (N / 2);          // 65536
    dim3 block(256);
    dim3 grid(threads / 256);                 // 256 blocks -> 1/CU, 4 waves/CU
    lif_scan_kernel<<<grid, block, 0, stream>>>(x, tau_mem, v_th, out);
}